// Round 2
// baseline (159.510 us; speedup 1.0000x reference)
//
#include <hip/hip_runtime.h>

#define BATCH  256
#define TLEN   8192
#define TPB    256
#define EPT    8                      // elements per thread
#define CHUNKS (TLEN / (TPB * EPT))   // 4 blocks per batch

// ---------------- style MLP: s = (relu(relu(md@mw1+mb1)@mw2+mb2))@mw3+mb3 ----------------
__global__ __launch_bounds__(128) void style_mlp_kernel(
    const float* __restrict__ metadata,
    const float* __restrict__ mw1, const float* __restrict__ mb1,
    const float* __restrict__ mw2, const float* __restrict__ mb2,
    const float* __restrict__ mw3, const float* __restrict__ mb3,
    float* __restrict__ s_out)
{
    const int b   = blockIdx.x;
    const int tid = threadIdx.x;
    __shared__ float md[16];
    __shared__ float h1[64];
    __shared__ float h2[128];

    if (tid < 16) md[tid] = metadata[b * 16 + tid];
    __syncthreads();

    if (tid < 64) {
        float a = mb1[tid];
        #pragma unroll
        for (int k = 0; k < 16; ++k) a = fmaf(md[k], mw1[k * 64 + tid], a);
        h1[tid] = fmaxf(a, 0.f);
    }
    __syncthreads();

    {
        float a = mb2[tid];
        #pragma unroll
        for (int k = 0; k < 64; ++k) a = fmaf(h1[k], mw2[k * 128 + tid], a);
        h2[tid] = fmaxf(a, 0.f);
    }
    __syncthreads();

    if (tid < 64) {
        float a = mb3[tid];
        #pragma unroll
        for (int k = 0; k < 128; ++k) a = fmaf(h2[k], mw3[k * 64 + tid], a);
        s_out[b * 64 + tid] = a;
    }
}

// ---------------- main pointwise pipeline ----------------
__device__ __forceinline__ void adain_lrelu(float (&h)[8], const float* sc, const float* sb)
{
    float mu = 0.f;
    #pragma unroll
    for (int j = 0; j < 8; ++j) mu += h[j];
    mu *= 0.125f;
    float var = 0.f;
    #pragma unroll
    for (int j = 0; j < 8; ++j) { float d = h[j] - mu; var = fmaf(d, d, var); }
    const float sigma = sqrtf(var * (1.f / 7.f)) + 1e-6f;   // ddof=1
    const float inv   = 1.f / sigma;
    #pragma unroll
    for (int j = 0; j < 8; ++j) {
        float t = fmaf(sc[j] * (h[j] - mu), inv, sb[j]);
        h[j] = t > 0.f ? t : 0.01f * t;
    }
}

__device__ __forceinline__ void matvec8(float (&h)[8], const float* W, const float* bias)
{
    float g[8];
    #pragma unroll
    for (int j = 0; j < 8; ++j) g[j] = bias[j];
    #pragma unroll
    for (int k = 0; k < 8; ++k) {
        const float hk = h[k];
        #pragma unroll
        for (int j = 0; j < 8; ++j) g[j] = fmaf(hk, W[k * 8 + j], g[j]);
    }
    #pragma unroll
    for (int j = 0; j < 8; ++j) h[j] = g[j];
}

__device__ __forceinline__ float pipeline_one(
    float v,
    const float* lw1, const float* lb1,
    const float* lw2, const float* lb2,
    const float* lw3, const float* lb3,
    const float* lw4, const float* lb4,
    const float* lw5, float lb5,
    const float (&sc)[4][8], const float (&sb)[4][8])
{
    float h[8];
    #pragma unroll
    for (int j = 0; j < 8; ++j) h[j] = fmaf(v, lw1[j], lb1[j]);

    adain_lrelu(h, sc[0], sb[0]);
    matvec8(h, lw2, lb2);
    adain_lrelu(h, sc[1], sb[1]);
    matvec8(h, lw3, lb3);
    adain_lrelu(h, sc[2], sb[2]);
    matvec8(h, lw4, lb4);
    adain_lrelu(h, sc[3], sb[3]);

    float o = lb5;
    #pragma unroll
    for (int k = 0; k < 8; ++k) o = fmaf(h[k], lw5[k], o);
    return o > 0.f ? o : 0.01f * o;
}

__global__ __launch_bounds__(TPB) void adain_main_kernel(
    const float* __restrict__ x, const float* __restrict__ s,
    const float* __restrict__ w1, const float* __restrict__ b1,
    const float* __restrict__ w2, const float* __restrict__ b2,
    const float* __restrict__ w3, const float* __restrict__ b3,
    const float* __restrict__ w4, const float* __restrict__ b4,
    const float* __restrict__ w5, const float* __restrict__ b5,
    float* __restrict__ out)
{
    __shared__ float lw1[8], lb1[8];
    __shared__ float lw2[64], lb2[8];
    __shared__ float lw3[64], lb3[8];
    __shared__ float lw4[64], lb4[8];
    __shared__ float lw5[8];
    __shared__ float lb5;
    __shared__ float sc[4][8], sb[4][8];

    const int tid   = threadIdx.x;
    const int b     = blockIdx.x / CHUNKS;
    const int chunk = blockIdx.x % CHUNKS;

    if (tid < 8) {
        lw1[tid] = w1[tid];  lb1[tid] = b1[tid];
        lb2[tid] = b2[tid];  lb3[tid] = b3[tid];
        lb4[tid] = b4[tid];  lw5[tid] = w5[tid];
    }
    if (tid == 0) lb5 = b5[0];
    if (tid >= 64  && tid < 128) { int i = tid - 64;  lw2[i] = w2[i]; }
    if (tid >= 128 && tid < 192) { int i = tid - 128; lw3[i] = w3[i]; }
    if (tid >= 192)              { int i = tid - 192; lw4[i] = w4[i]; }
    if (tid >= 8 && tid < 40) {
        // style layout: s[b, 16L + 2c] = scale, s[b, 16L + 2c + 1] = bias
        int i = tid - 8, L = i >> 3, c = i & 7;
        sc[L][c] = s[b * 64 + 16 * L + 2 * c];
        sb[L][c] = s[b * 64 + 16 * L + 2 * c + 1];
    }
    __syncthreads();

    const float4* __restrict__ x4   = (const float4*)x;
    float4* __restrict__       out4 = (float4*)out;
    const int base4 = (b * TLEN + chunk * (TPB * EPT)) >> 2;   // float4 index

    #pragma unroll
    for (int e = 0; e < EPT / 4; ++e) {                        // 2 iterations
        const int i4 = base4 + e * TPB + tid;
        const float4 v = x4[i4];
        float4 o;
        o.x = pipeline_one(v.x, lw1, lb1, lw2, lb2, lw3, lb3, lw4, lb4, lw5, lb5, sc, sb);
        o.y = pipeline_one(v.y, lw1, lb1, lw2, lb2, lw3, lb3, lw4, lb4, lw5, lb5, sc, sb);
        o.z = pipeline_one(v.z, lw1, lb1, lw2, lb2, lw3, lb3, lw4, lb4, lw5, lb5, sc, sb);
        o.w = pipeline_one(v.w, lw1, lb1, lw2, lb2, lw3, lb3, lw4, lb4, lw5, lb5, sc, sb);
        out4[i4] = o;
    }
}

extern "C" void kernel_launch(void* const* d_in, const int* in_sizes, int n_in,
                              void* d_out, int out_size, void* d_ws, size_t ws_size,
                              hipStream_t stream)
{
    const float* x        = (const float*)d_in[0];
    const float* metadata = (const float*)d_in[1];
    const float* mw1      = (const float*)d_in[2];
    const float* mb1      = (const float*)d_in[3];
    const float* mw2      = (const float*)d_in[4];
    const float* mb2      = (const float*)d_in[5];
    const float* mw3      = (const float*)d_in[6];
    const float* mb3      = (const float*)d_in[7];
    const float* w1       = (const float*)d_in[8];
    const float* b1       = (const float*)d_in[9];
    const float* w2       = (const float*)d_in[10];
    const float* b2       = (const float*)d_in[11];
    const float* w3       = (const float*)d_in[12];
    const float* b3       = (const float*)d_in[13];
    const float* w4       = (const float*)d_in[14];
    const float* b4       = (const float*)d_in[15];
    const float* w5       = (const float*)d_in[16];
    const float* b5       = (const float*)d_in[17];

    float* s_ws = (float*)d_ws;   // 256*64 fp32 style params

    style_mlp_kernel<<<BATCH, 128, 0, stream>>>(metadata, mw1, mb1, mw2, mb2, mw3, mb3, s_ws);
    adain_main_kernel<<<BATCH * CHUNKS, TPB, 0, stream>>>(
        x, s_ws, w1, b1, w2, b2, w3, b3, w4, b4, w5, b5, (float*)d_out);
}

// Round 3
// 117.536 us; speedup vs baseline: 1.3571x; 1.3571x over previous
//
#include <hip/hip_runtime.h>

#define BATCH  256
#define TLEN   8192
#define TPB    256
#define EPT    4                       // elements per thread (one float4)
#define CHUNKS (TLEN / (TPB * EPT))    // 8 blocks per batch

__device__ __forceinline__ float rowmean8(const float* __restrict__ p) {
    return (((p[0] + p[1]) + (p[2] + p[3])) + ((p[4] + p[5]) + (p[6] + p[7]))) * 0.125f;
}

__device__ __forceinline__ float lrelu(float t) { return fmaxf(t, 0.01f * t); }

// one fused kernel: per-block style MLP + weight centering + pointwise pipeline
__global__ __launch_bounds__(TPB, 4) void adain_fused_kernel(
    const float* __restrict__ x, const float* __restrict__ metadata,
    const float* __restrict__ mw1, const float* __restrict__ mb1,
    const float* __restrict__ mw2, const float* __restrict__ mb2,
    const float* __restrict__ mw3, const float* __restrict__ mb3,
    const float* __restrict__ w1, const float* __restrict__ b1,
    const float* __restrict__ w2, const float* __restrict__ b2,
    const float* __restrict__ w3, const float* __restrict__ b3,
    const float* __restrict__ w4, const float* __restrict__ b4,
    const float* __restrict__ w5, const float* __restrict__ b5,
    float* __restrict__ out)
{
    __shared__ float md[16];
    __shared__ float h1[64];
    __shared__ float h2[128];
    __shared__ float lsc[32], lsb[32];           // style scale/bias, [layer][8]
    __shared__ float wc2[64], wc3[64], wc4[64];  // column-centered weights
    __shared__ float cb2[8], cb3[8], cb4[8];     // centered biases
    __shared__ float la[8], lc[8];               // layer-1 centered affine
    __shared__ float lw5[8];
    __shared__ float lmisc[4];                   // A, B2, C, b5

    const int tid   = threadIdx.x;
    const int b     = blockIdx.x / CHUNKS;
    const int chunk = blockIdx.x % CHUNKS;

    // ---- phase 1: independent preloads / weight centering ----
    if (tid < 16) {
        md[tid] = metadata[b * 16 + tid];
    } else if (tid >= 64 && tid < 128) {
        int i = tid - 64;  wc2[i] = w2[i] - rowmean8(w2 + (i & 56));
    } else if (tid >= 128 && tid < 192) {
        int i = tid - 128; wc3[i] = w3[i] - rowmean8(w3 + (i & 56));
    } else if (tid >= 192) {
        int i = tid - 192; wc4[i] = w4[i] - rowmean8(w4 + (i & 56));
    } else if (tid >= 32 && tid < 40) {
        int j = tid - 32; cb2[j] = b2[j] - rowmean8(b2);
    } else if (tid >= 40 && tid < 48) {
        int j = tid - 40; cb3[j] = b3[j] - rowmean8(b3);
    } else if (tid >= 48 && tid < 56) {
        int j = tid - 48; cb4[j] = b4[j] - rowmean8(b4);
    } else if (tid >= 56 && tid < 64) {
        int j = tid - 56; la[j] = w1[j] - rowmean8(w1); lc[j] = b1[j] - rowmean8(b1);
    } else if (tid >= 16 && tid < 24) {
        int j = tid - 16; lw5[j] = w5[j];
    } else if (tid == 24) {
        lmisc[3] = b5[0];
    }
    __syncthreads();

    // ---- phase 2: style layer 1 + layer-1 variance polynomial ----
    if (tid < 64) {
        float a = mb1[tid];
        #pragma unroll
        for (int k = 0; k < 16; ++k) a = fmaf(md[k], mw1[k * 64 + tid], a);
        h1[tid] = fmaxf(a, 0.f);
    } else if (tid == 224) {
        float A = 0.f, Bh = 0.f, C = 0.f;
        #pragma unroll
        for (int j = 0; j < 8; ++j) {
            A  = fmaf(la[j], la[j], A);
            Bh = fmaf(la[j], lc[j], Bh);
            C  = fmaf(lc[j], lc[j], C);
        }
        lmisc[0] = A; lmisc[1] = 2.f * Bh; lmisc[2] = C;
    }
    __syncthreads();

    // ---- phase 3: style layer 2 ----
    if (tid < 128) {
        float a = mb2[tid];
        #pragma unroll 16
        for (int k = 0; k < 64; ++k) a = fmaf(h1[k], mw2[k * 128 + tid], a);
        h2[tid] = fmaxf(a, 0.f);
    }
    __syncthreads();

    // ---- phase 4: style layer 3, scatter into scale/bias arrays ----
    if (tid < 64) {
        float a = mb3[tid];
        #pragma unroll 16
        for (int k = 0; k < 128; ++k) a = fmaf(h2[k], mw3[k * 64 + tid], a);
        // s layout: [L][c][{scale,bias}] ; tid = 16L + 2c + which
        int L = tid >> 4, c = (tid >> 1) & 7;
        ((tid & 1) ? lsb : lsc)[L * 8 + c] = a;
    }
    __syncthreads();

    const float cA  = lmisc[0], cB2 = lmisc[1], cC = lmisc[2], lb5 = lmisc[3];

    // ---- main pointwise pipeline: 4 elements per thread ----
    const float4* __restrict__ x4   = (const float4*)x;
    float4* __restrict__       out4 = (float4*)out;
    const int i4 = b * (TLEN / 4) + chunk * TPB + tid;

    const float4 v = x4[i4];
    const float ve[4] = {v.x, v.y, v.z, v.w};
    float h[4][8];

    // layer 1 + adain1 (affine in v; variance via quadratic)
    #pragma unroll
    for (int e = 0; e < 4; ++e) {
        float d[8];
        #pragma unroll
        for (int j = 0; j < 8; ++j) d[j] = fmaf(ve[e], la[j], lc[j]);
        float var = fmaxf(fmaf(ve[e], fmaf(ve[e], cA, cB2), cC), 0.f);
        float inv = __builtin_amdgcn_rcpf(
                        __builtin_amdgcn_sqrtf(var * (1.f / 7.f)) + 1e-6f);
        #pragma unroll
        for (int j = 0; j < 8; ++j)
            h[e][j] = lrelu(fmaf(d[j] * inv, lsc[j], lsb[j]));
    }

    // layers 2..4: centered matvec + adain
    const float* wcs[3] = {wc2, wc3, wc4};
    const float* cbs[3] = {cb2, cb3, cb4};
    #pragma unroll
    for (int l = 0; l < 3; ++l) {
        const float* __restrict__ wc = wcs[l];
        const float* __restrict__ cb = cbs[l];
        const float* __restrict__ sc = &lsc[(l + 1) * 8];
        const float* __restrict__ sb = &lsb[(l + 1) * 8];

        float g[4][8];
        #pragma unroll
        for (int e = 0; e < 4; ++e)
            #pragma unroll
            for (int j = 0; j < 8; ++j) g[e][j] = cb[j];

        #pragma unroll
        for (int k = 0; k < 8; ++k) {
            const float4 wa = *(const float4*)(wc + k * 8);
            const float4 wb = *(const float4*)(wc + k * 8 + 4);
            const float wr[8] = {wa.x, wa.y, wa.z, wa.w, wb.x, wb.y, wb.z, wb.w};
            #pragma unroll
            for (int e = 0; e < 4; ++e) {
                const float hk = h[e][k];
                #pragma unroll
                for (int j = 0; j < 8; ++j) g[e][j] = fmaf(hk, wr[j], g[e][j]);
            }
        }

        #pragma unroll
        for (int e = 0; e < 4; ++e) {
            float var = 0.f;
            #pragma unroll
            for (int j = 0; j < 8; ++j) var = fmaf(g[e][j], g[e][j], var);
            float inv = __builtin_amdgcn_rcpf(
                            __builtin_amdgcn_sqrtf(var * (1.f / 7.f)) + 1e-6f);
            #pragma unroll
            for (int j = 0; j < 8; ++j)
                h[e][j] = lrelu(fmaf(g[e][j] * inv, sc[j], sb[j]));
        }
    }

    // final projection + lrelu
    float oe[4];
    #pragma unroll
    for (int e = 0; e < 4; ++e) {
        float a = lb5;
        #pragma unroll
        for (int k = 0; k < 8; ++k) a = fmaf(h[e][k], lw5[k], a);
        oe[e] = lrelu(a);
    }
    out4[i4] = make_float4(oe[0], oe[1], oe[2], oe[3]);
}

extern "C" void kernel_launch(void* const* d_in, const int* in_sizes, int n_in,
                              void* d_out, int out_size, void* d_ws, size_t ws_size,
                              hipStream_t stream)
{
    const float* x        = (const float*)d_in[0];
    const float* metadata = (const float*)d_in[1];
    const float* mw1      = (const float*)d_in[2];
    const float* mb1      = (const float*)d_in[3];
    const float* mw2      = (const float*)d_in[4];
    const float* mb2      = (const float*)d_in[5];
    const float* mw3      = (const float*)d_in[6];
    const float* mb3      = (const float*)d_in[7];
    const float* w1       = (const float*)d_in[8];
    const float* b1       = (const float*)d_in[9];
    const float* w2       = (const float*)d_in[10];
    const float* b2       = (const float*)d_in[11];
    const float* w3       = (const float*)d_in[12];
    const float* b3       = (const float*)d_in[13];
    const float* w4       = (const float*)d_in[14];
    const float* b4       = (const float*)d_in[15];
    const float* w5       = (const float*)d_in[16];
    const float* b5       = (const float*)d_in[17];

    adain_fused_kernel<<<BATCH * CHUNKS, TPB, 0, stream>>>(
        x, metadata, mw1, mb1, mw2, mb2, mw3, mb3,
        w1, b1, w2, b2, w3, b3, w4, b4, w5, b5, (float*)d_out);
}

// Round 4
// 113.216 us; speedup vs baseline: 1.4089x; 1.0382x over previous
//
#include <hip/hip_runtime.h>

#define BATCH   256
#define TLEN    8192
#define TPB     256
#define EPT     4                       // elements per thread (one float4)
#define CHUNKS  (TLEN / (TPB * EPT))    // 8 blocks per batch
#define PSTRIDE 320                     // floats per batch param record (304 used)

// packed per-batch param record layout (floats):
//   0: la'   (8)  = (w1 - mean) * sc1
//   8: lc'   (8)  = (b1 - mean) * sc1
//  16: sb1   (8)
//  24: A, 2B, C, b5                     (layer-1 variance quadratic, final bias)
//  32 + 88*l (l=0..2): wc (64), cb (8), sc (8), sb (8)   for layers 2..4
// 296: w5    (8)
// total 304

__device__ __forceinline__ float rowmean8(const float* __restrict__ p) {
    return (((p[0] + p[1]) + (p[2] + p[3])) + ((p[4] + p[5]) + (p[6] + p[7]))) * 0.125f;
}

__device__ __forceinline__ float lrelu(float t) { return fmaxf(t, 0.01f * t); }

// ---------------- prep: style MLP + weight centering + packing, one block per batch ----------------
__global__ __launch_bounds__(128) void prep_kernel(
    const float* __restrict__ metadata,
    const float* __restrict__ mw1, const float* __restrict__ mb1,
    const float* __restrict__ mw2, const float* __restrict__ mb2,
    const float* __restrict__ mw3, const float* __restrict__ mb3,
    const float* __restrict__ w1, const float* __restrict__ b1,
    const float* __restrict__ w2, const float* __restrict__ b2,
    const float* __restrict__ w3, const float* __restrict__ b3,
    const float* __restrict__ w4, const float* __restrict__ b4,
    const float* __restrict__ w5, const float* __restrict__ b5,
    float* __restrict__ P)
{
    const int b   = blockIdx.x;
    const int tid = threadIdx.x;
    __shared__ float md[16];
    __shared__ float h1[64];
    __shared__ float h2[128];
    __shared__ float s[64];
    __shared__ float la[8], lc[8], sc1[8];

    if (tid < 16) md[tid] = metadata[b * 16 + tid];
    __syncthreads();

    if (tid < 64) {
        float a = mb1[tid];
        #pragma unroll
        for (int k = 0; k < 16; ++k) a = fmaf(md[k], mw1[k * 64 + tid], a);
        h1[tid] = fmaxf(a, 0.f);
    }
    __syncthreads();

    {
        float a = mb2[tid];
        #pragma unroll 16
        for (int k = 0; k < 64; ++k) a = fmaf(h1[k], mw2[k * 128 + tid], a);
        h2[tid] = fmaxf(a, 0.f);
    }
    __syncthreads();

    if (tid < 64) {
        float a = mb3[tid];
        #pragma unroll 16
        for (int k = 0; k < 128; ++k) a = fmaf(h2[k], mw3[k * 64 + tid], a);
        s[tid] = a;                 // s[16L + 2c] = scale, s[16L + 2c + 1] = bias
    }
    if (tid < 8) {
        la[tid]  = w1[tid] - rowmean8(w1);
        lc[tid]  = b1[tid] - rowmean8(b1);
    }
    __syncthreads();
    if (tid < 8) sc1[tid] = s[2 * tid];
    __syncthreads();

    float* __restrict__ p = P + b * PSTRIDE;

    if (tid == 0) {
        float A = 0.f, B = 0.f, C = 0.f;
        #pragma unroll
        for (int j = 0; j < 8; ++j) {
            A = fmaf(la[j], la[j], A);
            B = fmaf(la[j], lc[j], B);
            C = fmaf(lc[j], lc[j], C);
        }
        p[24] = A; p[25] = 2.f * B; p[26] = C; p[27] = b5[0];
    }
    if (tid < 8) {
        p[tid]      = la[tid] * sc1[tid];
        p[8 + tid]  = lc[tid] * sc1[tid];
        p[16 + tid] = s[2 * tid + 1];                    // sb1
        // layer 2..4 small params
        p[32 + 64 + tid]       = b2[tid] - rowmean8(b2);
        p[32 + 72 + tid]       = s[16 + 2 * tid];
        p[32 + 80 + tid]       = s[16 + 2 * tid + 1];
        p[120 + 64 + tid]      = b3[tid] - rowmean8(b3);
        p[120 + 72 + tid]      = s[32 + 2 * tid];
        p[120 + 80 + tid]      = s[32 + 2 * tid + 1];
        p[208 + 64 + tid]      = b4[tid] - rowmean8(b4);
        p[208 + 72 + tid]      = s[48 + 2 * tid];
        p[208 + 80 + tid]      = s[48 + 2 * tid + 1];
        p[296 + tid]           = w5[tid];
    }
    if (tid >= 64) {
        int i = tid - 64;                                // 0..63
        p[32 + i]  = w2[i] - rowmean8(w2 + (i & 56));
        p[120 + i] = w3[i] - rowmean8(w3 + (i & 56));
        p[208 + i] = w4[i] - rowmean8(w4 + (i & 56));
    }
}

// ---------------- main: pure pointwise pipeline, params from packed record ----------------
__global__ __launch_bounds__(TPB, 4) void adain_main_kernel(
    const float* __restrict__ x, const float* __restrict__ P, float* __restrict__ out)
{
    __shared__ float4 pbuf[76];                          // 304 floats
    float* __restrict__ p = (float*)pbuf;

    const int tid   = threadIdx.x;
    const int b     = blockIdx.x / CHUNKS;
    const int chunk = blockIdx.x % CHUNKS;

    if (tid < 76) pbuf[tid] = ((const float4*)(P + b * PSTRIDE))[tid];
    __syncthreads();

    const float cA = p[24], cB2 = p[25], cC = p[26], lb5 = p[27];

    const float4* __restrict__ x4   = (const float4*)x;
    float4* __restrict__       out4 = (float4*)out;
    const int i4 = b * (TLEN / 4) + chunk * TPB + tid;

    const float4 v = x4[i4];
    const float ve[4] = {v.x, v.y, v.z, v.w};
    float h[4][8];

    // layer 1 + adain1 (sc1 pre-folded into la'/lc'; variance via quadratic)
    #pragma unroll
    for (int e = 0; e < 4; ++e) {
        float var = fmaxf(fmaf(ve[e], fmaf(ve[e], cA, cB2), cC), 0.f);
        float inv = __builtin_amdgcn_rcpf(
                        __builtin_amdgcn_sqrtf(var * (1.f / 7.f)) + 1e-6f);
        #pragma unroll
        for (int j = 0; j < 8; ++j) {
            float d = fmaf(ve[e], p[j], p[8 + j]);
            h[e][j] = lrelu(fmaf(d, inv, p[16 + j]));
        }
    }

    // layers 2..4: centered matvec + adain
    #pragma unroll
    for (int l = 0; l < 3; ++l) {
        const float* __restrict__ wc = p + 32 + l * 88;
        const float* __restrict__ cb = wc + 64;
        const float* __restrict__ sc = wc + 72;
        const float* __restrict__ sb = wc + 80;

        float g[4][8];
        #pragma unroll
        for (int e = 0; e < 4; ++e)
            #pragma unroll
            for (int j = 0; j < 8; ++j) g[e][j] = cb[j];

        #pragma unroll
        for (int k = 0; k < 8; ++k) {
            const float4 wa = *(const float4*)(wc + k * 8);
            const float4 wb = *(const float4*)(wc + k * 8 + 4);
            const float wr[8] = {wa.x, wa.y, wa.z, wa.w, wb.x, wb.y, wb.z, wb.w};
            #pragma unroll
            for (int e = 0; e < 4; ++e) {
                const float hk = h[e][k];
                #pragma unroll
                for (int j = 0; j < 8; ++j) g[e][j] = fmaf(hk, wr[j], g[e][j]);
            }
        }

        #pragma unroll
        for (int e = 0; e < 4; ++e) {
            float var = 0.f;
            #pragma unroll
            for (int j = 0; j < 8; ++j) var = fmaf(g[e][j], g[e][j], var);
            float inv = __builtin_amdgcn_rcpf(
                            __builtin_amdgcn_sqrtf(var * (1.f / 7.f)) + 1e-6f);
            #pragma unroll
            for (int j = 0; j < 8; ++j)
                h[e][j] = lrelu(fmaf(g[e][j] * inv, sc[j], sb[j]));
        }
    }

    // final projection + lrelu
    float oe[4];
    #pragma unroll
    for (int e = 0; e < 4; ++e) {
        float a = lb5;
        #pragma unroll
        for (int k = 0; k < 8; ++k) a = fmaf(h[e][k], p[296 + k], a);
        oe[e] = lrelu(a);
    }
    out4[i4] = make_float4(oe[0], oe[1], oe[2], oe[3]);
}

extern "C" void kernel_launch(void* const* d_in, const int* in_sizes, int n_in,
                              void* d_out, int out_size, void* d_ws, size_t ws_size,
                              hipStream_t stream)
{
    const float* x        = (const float*)d_in[0];
    const float* metadata = (const float*)d_in[1];
    const float* mw1      = (const float*)d_in[2];
    const float* mb1      = (const float*)d_in[3];
    const float* mw2      = (const float*)d_in[4];
    const float* mb2      = (const float*)d_in[5];
    const float* mw3      = (const float*)d_in[6];
    const float* mb3      = (const float*)d_in[7];
    const float* w1       = (const float*)d_in[8];
    const float* b1       = (const float*)d_in[9];
    const float* w2       = (const float*)d_in[10];
    const float* b2       = (const float*)d_in[11];
    const float* w3       = (const float*)d_in[12];
    const float* b3       = (const float*)d_in[13];
    const float* w4       = (const float*)d_in[14];
    const float* b4       = (const float*)d_in[15];
    const float* w5       = (const float*)d_in[16];
    const float* b5       = (const float*)d_in[17];

    float* P = (float*)d_ws;   // 256 * PSTRIDE floats = 327 KB, ws is larger

    prep_kernel<<<BATCH, 128, 0, stream>>>(
        metadata, mw1, mb1, mw2, mb2, mw3, mb3,
        w1, b1, w2, b2, w3, b3, w4, b4, w5, b5, P);
    adain_main_kernel<<<BATCH * CHUNKS, TPB, 0, stream>>>(x, P, (float*)d_out);
}